// Round 2
// baseline (298.651 us; speedup 1.0000x reference)
//
#include <hip/hip_runtime.h>
#include <stdint.h>

// ---------------- constants ----------------
#define NCLS 20
#define STG_PER_WAVE 640
#define STG_TRIG 512
#define SURV_CAP 2048

__device__ __forceinline__ float sigm(float x) { return 1.0f / (1.0f + expf(-x)); }

// ---------------- K0: init ws ----------------
__global__ void k_init(unsigned int* hdr, unsigned int* hist) {
    int t = threadIdx.x;
    for (int i = t; i < 64; i += 1024) hdr[i] = 0u;
    for (int i = t; i < 3 * 4096; i += 1024) hist[i] = 0u;
}

// ---------------- K1/K2: streaming score pass ----------------
// hdr[0..2]  : main-pass append counts per level
// hdr[4..6]  : fallback append counts per level
// hdr[8..10] : Tsel bits per level
// hdr[12..14]: survivor counts per level
// Block decomposition: one block = 512 pixels x 1 anchor (obj channel + 20 cls channels).
// L0: 200 tiles x 3 anchors = 600 blocks; L1: 50x3=150; L2: 13x3=39. Total 789.
template<int FB>
__global__ __launch_bounds__(256) void k_score(
    const float* __restrict__ obj0, const float* __restrict__ cls0,
    const float* __restrict__ obj1, const float* __restrict__ cls1,
    const float* __restrict__ obj2, const float* __restrict__ cls2,
    unsigned int* hdr, unsigned int* hist,
    unsigned long long* buf0, unsigned long long* buf1, unsigned long long* buf2,
    int cap0, int cap1, int cap2)
{
    int b = blockIdx.x;
    int L, tile, a, W;
    const float *obj, *cls; unsigned long long* gbuf; int cap;
    if (b < 600)      { L = 0; tile = b % 200;        a = b / 200;        W = 320; obj = obj0; cls = cls0; gbuf = buf0; cap = cap0; }
    else if (b < 750) { int bb = b - 600; L = 1; tile = bb % 50; a = bb / 50; W = 160; obj = obj1; cls = cls1; gbuf = buf1; cap = cap1; }
    else              { int bb = b - 750; L = 2; tile = bb % 13; a = bb / 13; W = 80;  obj = obj2; cls = cls2; gbuf = buf2; cap = cap2; }
    const int P = W * W;
    if (FB) { if (hdr[L] >= 100u) return; }   // fallback not needed for this level

    __shared__ unsigned long long stage[4 * STG_PER_WAVE];
    __shared__ unsigned int lhist[4096];
    __shared__ int wcnt[4];

    const int t = threadIdx.x;
    const int wid = t >> 6, lane = t & 63;
    for (int i = t; i < 4096; i += 256) lhist[i] = 0u;
    if (lane == 0) wcnt[wid] = 0;
    __syncthreads();

    unsigned long long* wstage = stage + wid * STG_PER_WAVE;

    const int p0 = tile * 512 + t * 2;       // two pixels per thread (P is even for all levels)
    const bool act = p0 < P;

    float so0 = 0.f, so1 = 0.f;
    if (act) {
        float2 ov = *(const float2*)(obj + (size_t)a * P + p0);
        so0 = sigm(ov.x); so1 = sigm(ov.y);
    }
    #pragma unroll
    for (int c = 0; c < NCLS; c++) {
        if (act) {
            float2 cv = *(const float2*)(cls + (size_t)(a * NCLS + c) * P + p0);
            float s0 = so0 * sigm(cv.x);
            float s1 = so1 * sigm(cv.y);
            #pragma unroll
            for (int q = 0; q < 2; q++) {
                float s = q ? s1 : s0;
                unsigned int bits = __float_as_uint(s);
                if (!FB && s >= 0.5f) {   // histogram only in main pass (no double count)
                    unsigned int bin = (bits - 0x3F000000u) >> 11;
                    if (bin > 4095u) bin = 4095u;
                    atomicAdd(&lhist[bin], 1u);
                }
                bool take = FB ? (s <= 0.7f) : (s > 0.7f);
                if (take) {
                    unsigned int ti = (unsigned int)(((p0 + q) * 3 + a) * NCLS + c);
                    unsigned long long key =
                        ((unsigned long long)bits << 32) | (unsigned long long)(0xFFFFFFFFu - ti);
                    int pos = atomicAdd(&wcnt[wid], 1);
                    if (pos < STG_PER_WAVE) wstage[pos] = key;
                }
            }
        }
        // wave-uniform flush check (no block barrier; wave LDS ops are in-order).
        // Max growth between checks = 128 (64 lanes x 2 px); trigger at 512, cap 640.
        if (wcnt[wid] >= STG_TRIG) {
            int n = wcnt[wid]; if (n > STG_PER_WAVE) n = STG_PER_WAVE;
            unsigned int base = 0;
            if (lane == 0) {
                if (FB) base = hdr[L] + atomicAdd(&hdr[4 + L], (unsigned int)n);
                else    base = atomicAdd(&hdr[L], (unsigned int)n);
            }
            base = __shfl(base, 0);
            for (int i = lane; i < n; i += 64) {
                unsigned int gp = base + i;
                if (gp < (unsigned int)cap) gbuf[gp] = wstage[i];
            }
            if (lane == 0) wcnt[wid] = 0;
        }
    }
    // final wave flush
    {
        int n = wcnt[wid]; if (n > STG_PER_WAVE) n = STG_PER_WAVE;
        if (n > 0) {
            unsigned int base = 0;
            if (lane == 0) {
                if (FB) base = hdr[L] + atomicAdd(&hdr[4 + L], (unsigned int)n);
                else    base = atomicAdd(&hdr[L], (unsigned int)n);
            }
            base = __shfl(base, 0);
            for (int i = lane; i < n; i += 64) {
                unsigned int gp = base + i;
                if (gp < (unsigned int)cap) gbuf[gp] = wstage[i];
            }
        }
    }
    if (!FB) {
        __syncthreads();
        for (int i = t; i < 4096; i += 256) {
            unsigned int v = lhist[i];
            if (v) atomicAdd(&hist[L * 4096 + i], v);
        }
    }
}

// ---------------- K3: histogram suffix-scan -> per-level selection threshold ----------------
__global__ void k_scan(unsigned int* hdr, const unsigned int* __restrict__ hist) {
    __shared__ unsigned int part[512];
    int t = threadIdx.x;
    for (int L = 0; L < 3; L++) {
        unsigned int c[8]; unsigned int s = 0;
        #pragma unroll
        for (int k = 0; k < 8; k++) {
            int rev = t * 8 + k;                      // rev 0 == highest bin
            c[k] = hist[L * 4096 + (4095 - rev)];
            s += c[k];
        }
        part[t] = s;
        __syncthreads();
        for (int off = 1; off < 512; off <<= 1) {     // Hillis-Steele inclusive scan
            unsigned int v = (t >= off) ? part[t - off] : 0u;
            __syncthreads();
            part[t] += v;
            __syncthreads();
        }
        unsigned int incl = part[t];
        unsigned int excl = incl - s;
        // if total < 100, Tsel stays 0 (select everything in buffer)
        if (excl < 100u && incl >= 100u) {
            unsigned int cum = excl;
            #pragma unroll
            for (int k = 0; k < 8; k++) {
                cum += c[k];
                if (cum >= 100u) {
                    int bin = 4095 - (t * 8 + k);
                    hdr[8 + L] = 0x3F000000u + ((unsigned int)bin << 11);
                    break;
                }
            }
        }
        __syncthreads();
    }
}

// ---------------- K4: compact survivors (>= Tsel) ----------------
__global__ void k_compact(unsigned int* hdr,
                          const unsigned long long* __restrict__ buf0,
                          const unsigned long long* __restrict__ buf1,
                          const unsigned long long* __restrict__ buf2,
                          int cap0, int cap1, int cap2,
                          unsigned long long* surv)
{
    int gt = blockIdx.x * blockDim.x + threadIdx.x;
    int gstep = gridDim.x * blockDim.x;
    int lane = threadIdx.x & 63;
    for (int L = 0; L < 3; L++) {
        const unsigned long long* buf = (L == 0) ? buf0 : (L == 1 ? buf1 : buf2);
        int cap = (L == 0) ? cap0 : (L == 1 ? cap1 : cap2);
        unsigned int cnt = hdr[L] + hdr[4 + L];
        int n = (int)((cnt < (unsigned int)cap) ? cnt : (unsigned int)cap);
        unsigned int ts = hdr[8 + L];
        for (int i = gt; i < n; i += gstep) {
            unsigned long long k = buf[i];
            bool takeIt = (unsigned int)(k >> 32) >= ts;
            unsigned long long m = __ballot(takeIt);
            if (takeIt) {
                int lead = __ffsll((long long)m) - 1;
                int pref = __popcll(m & ((1ull << lane) - 1ull));
                unsigned int base = 0;
                if (lane == lead) base = atomicAdd(&hdr[12 + L], (unsigned int)__popcll(m));
                base = __shfl(base, lead);
                unsigned int pos = base + (unsigned int)pref;
                if (pos < SURV_CAP) surv[L * SURV_CAP + pos] = k;
            }
        }
    }
}

// ---------------- K5: final select + decode + sort + NMS + output ----------------
__global__ __launch_bounds__(512) void k_final(
    const unsigned int* __restrict__ hdr,
    const unsigned long long* __restrict__ surv,
    const float* __restrict__ reg0, const float* __restrict__ reg1, const float* __restrict__ reg2,
    float* __restrict__ out)
{
    const int t = threadIdx.x;
    __shared__ unsigned long long topk[300];
    __shared__ float bx[300][4];
    __shared__ float sc[300];
    __shared__ int   lb[300];
    __shared__ unsigned long long key2[300];
    __shared__ float sbx[300][4];
    __shared__ float ssc[300];
    __shared__ int   slb[300];
    __shared__ float sar[300];
    __shared__ unsigned long long supmat[300][5];
    __shared__ unsigned char keepA[300];

    for (int i = t; i < 300; i += 512) topk[i] = 0ull;
    __syncthreads();

    // per-level exact rank select (keys unique)
    for (int L = 0; L < 3; L++) {
        int n = (int)hdr[12 + L]; if (n > SURV_CAP) n = SURV_CAP;
        const unsigned long long* sv = surv + L * SURV_CAP;
        for (int i = t; i < n; i += 512) {
            unsigned long long ki = sv[i];
            int r = 0;
            for (int j = 0; j < n; j++) r += (sv[j] > ki);
            if (r < 100) topk[L * 100 + r] = ki;
        }
    }
    __syncthreads();

    const int   Wl[3] = {320, 160, 80};
    const float Sl[3] = {8.f, 16.f, 32.f};
    const float AW[3][3] = {{12.f, 19.f, 40.f}, {36.f, 76.f, 72.f}, {142.f, 192.f, 459.f}};
    const float AH[3][3] = {{16.f, 36.f, 28.f}, {75.f, 55.f, 146.f}, {110.f, 243.f, 401.f}};

    for (int i = t; i < 300; i += 512) {
        unsigned long long k = topk[i];
        int L = i / 100;
        float s = __uint_as_float((unsigned int)(k >> 32));
        unsigned int ti = 0xFFFFFFFFu - (unsigned int)k;
        float x1 = 0.f, y1 = 0.f, x2 = 0.f, y2 = 0.f; int c = 0;
        if (k != 0ull) {
            c = (int)(ti % NCLS);
            unsigned int na = ti / NCLS;
            int a = (int)(na % 3);
            int p = (int)(na / 3);
            int W = Wl[L]; int P = W * W;
            int px = p % W, py = p / W;
            const float* reg = (L == 0) ? reg0 : (L == 1 ? reg1 : reg2);
            float tx = reg[(a * 4 + 0) * P + p];
            float ty = reg[(a * 4 + 1) * P + p];
            float tw = reg[(a * 4 + 2) * P + p];
            float th = reg[(a * 4 + 3) * P + p];
            float st = Sl[L];
            float cx = (sigm(tx) * 3.0f - 1.5f + ((float)px + 0.5f)) * st;
            float cy = (sigm(ty) * 3.0f - 1.5f + ((float)py + 0.5f)) * st;
            float w = expf(tw) * AW[L][a];
            float h = expf(th) * AH[L][a];
            x1 = cx - 0.5f * w; y1 = cy - 0.5f * h; x2 = cx + 0.5f * w; y2 = cy + 0.5f * h;
        } else {
            s = 0.f;
        }
        bx[i][0] = x1; bx[i][1] = y1; bx[i][2] = x2; bx[i][3] = y2;
        sc[i] = s; lb[i] = c;
        // stable argsort(-scores): score desc, concat-position asc
        key2[i] = (k & 0xFFFFFFFF00000000ull) | (unsigned long long)(299 - i);
    }
    __syncthreads();

    for (int i = t; i < 300; i += 512) {
        unsigned long long ki = key2[i];
        int r = 0;
        for (int j = 0; j < 300; j++) r += (key2[j] > ki);
        sbx[r][0] = bx[i][0]; sbx[r][1] = bx[i][1]; sbx[r][2] = bx[i][2]; sbx[r][3] = bx[i][3];
        ssc[r] = sc[i]; slb[r] = lb[i];
    }
    __syncthreads();
    for (int i = t; i < 300; i += 512)
        sar[i] = (sbx[i][2] - sbx[i][0]) * (sbx[i][3] - sbx[i][1]);
    __syncthreads();

    // suppression matrix rows as bitmasks
    for (int i = t; i < 300; i += 512) {
        float ax1 = sbx[i][0], ay1 = sbx[i][1], ax2 = sbx[i][2], ay2 = sbx[i][3], aa = sar[i];
        int al = slb[i];
        unsigned long long wds[5] = {0ull, 0ull, 0ull, 0ull, 0ull};
        for (int j = 0; j < 300; j++) {
            float xx1 = fmaxf(ax1, sbx[j][0]);
            float yy1 = fmaxf(ay1, sbx[j][1]);
            float xx2 = fminf(ax2, sbx[j][2]);
            float yy2 = fminf(ay2, sbx[j][3]);
            float iw = fmaxf(1e-10f, xx2 - xx1);
            float ih = fmaxf(1e-10f, yy2 - yy1);
            float inter = iw * ih;
            float iou = inter / (aa + sar[j] - inter);
            if (iou > 0.5f && al == slb[j]) wds[j >> 6] |= (1ull << (j & 63));
        }
        #pragma unroll
        for (int w = 0; w < 5; w++) supmat[i][w] = wds[w];
    }
    __syncthreads();

    // serial greedy on bitmasks
    if (t == 0) {
        unsigned long long sup[5] = {0ull, 0ull, 0ull, 0ull, 0ull};
        for (int i = 0; i < 300; i++) {
            int w = i >> 6, bb = i & 63;
            bool si = (sup[w] >> bb) & 1ull;
            bool kept = (!si) && (ssc[i] > 0.01f);
            keepA[i] = kept ? 1 : 0;
            if (kept) {
                #pragma unroll
                for (int ww = 0; ww < 5; ww++) {
                    unsigned long long gm;
                    if (ww < w)       gm = 0ull;
                    else if (ww == w) gm = (bb == 63) ? 0ull : ((~0ull) << (bb + 1));
                    else              gm = ~0ull;
                    sup[ww] |= supmat[i][ww] & gm;
                }
            }
        }
    }
    __syncthreads();

    for (int i = t; i < 300; i += 512) {
        out[i * 4 + 0] = sbx[i][0];
        out[i * 4 + 1] = sbx[i][1];
        out[i * 4 + 2] = sbx[i][2];
        out[i * 4 + 3] = sbx[i][3];
        float kp = keepA[i] ? 1.f : 0.f;
        out[1200 + i] = ssc[i] * kp;
        out[1500 + i] = (float)slb[i];
        out[1800 + i] = kp;
    }
}

// ---------------- launch ----------------
extern "C" void kernel_launch(void* const* d_in, const int* in_sizes, int n_in,
                              void* d_out, int out_size, void* d_ws, size_t ws_size,
                              hipStream_t stream)
{
    const float* obj0 = (const float*)d_in[0];
    const float* cls0 = (const float*)d_in[1];
    const float* reg0 = (const float*)d_in[2];
    const float* obj1 = (const float*)d_in[3];
    const float* cls1 = (const float*)d_in[4];
    const float* reg1 = (const float*)d_in[5];
    const float* obj2 = (const float*)d_in[6];
    const float* cls2 = (const float*)d_in[7];
    const float* reg2 = (const float*)d_in[8];

    char* ws = (char*)d_ws;
    unsigned int* hdr  = (unsigned int*)ws;                       // 256 B
    unsigned int* hist = (unsigned int*)(ws + 256);               // 48 KB
    unsigned long long* surv = (unsigned long long*)(ws + 256 + 49152); // 48 KB
    const size_t off = 131072;

    size_t avail = (ws_size > off) ? (ws_size - off) : 0;
    long long ents = (long long)(avail / 8);
    long long cap0 = ents * 16 / 21; if (cap0 > 6144000LL) cap0 = 6144000LL;
    long long cap1 = ents * 4 / 21;  if (cap1 > 1536000LL) cap1 = 1536000LL;
    long long cap2 = ents * 1 / 21;  if (cap2 > 384000LL)  cap2 = 384000LL;
    if (cap0 < 1) cap0 = 1; if (cap1 < 1) cap1 = 1; if (cap2 < 1) cap2 = 1;

    unsigned long long* buf0 = (unsigned long long*)(ws + off);
    unsigned long long* buf1 = buf0 + cap0;
    unsigned long long* buf2 = buf1 + cap1;

    k_init<<<1, 1024, 0, stream>>>(hdr, hist);
    k_score<0><<<789, 256, 0, stream>>>(obj0, cls0, obj1, cls1, obj2, cls2,
                                        hdr, hist, buf0, buf1, buf2,
                                        (int)cap0, (int)cap1, (int)cap2);
    k_score<1><<<789, 256, 0, stream>>>(obj0, cls0, obj1, cls1, obj2, cls2,
                                        hdr, hist, buf0, buf1, buf2,
                                        (int)cap0, (int)cap1, (int)cap2);
    k_scan<<<1, 512, 0, stream>>>(hdr, hist);
    k_compact<<<128, 256, 0, stream>>>(hdr, buf0, buf1, buf2,
                                       (int)cap0, (int)cap1, (int)cap2, surv);
    k_final<<<1, 512, 0, stream>>>(hdr, surv, reg0, reg1, reg2, (float*)d_out);
}